// Round 6
// baseline (52.294 us; speedup 1.0000x reference)
//
#include <hip/hip_runtime.h>

#define EPS 1e-5f

typedef float f32x4 __attribute__((ext_vector_type(4)));
typedef short bf16x8 __attribute__((ext_vector_type(8)));

__device__ __forceinline__ unsigned short f2bf(float f) {
  unsigned int u = __builtin_bit_cast(unsigned int, f);
  u = (u + 0x7FFFu + ((u >> 16) & 1u)) >> 16;
  return (unsigned short)u;
}

// ---------------------------------------------------------------------------
// Prep (verified): fold BN into weights; emit both weight matrices in MFMA
// A-fragment layout (bf16), REFERENCE k-order.
// Frag element: idx = ((ks*CT + ct)*64 + lane)*8 + j
//   <-> A[ch = ct*16 + (lane&15)][k = ks*32 + (lane>>4)*8 + j]
// w2: K 528 -> 544 zero-padded (17 ks, CT=16).  w1: K=256 exact (8 ks, CT=2).
// ---------------------------------------------------------------------------
__global__ __launch_bounds__(256) void k_prep(
    const float* __restrict__ w1, const float* __restrict__ b1,
    const float* __restrict__ g1, const float* __restrict__ be1,
    const float* __restrict__ m1, const float* __restrict__ v1,
    const float* __restrict__ w2, const float* __restrict__ b2,
    const float* __restrict__ g2, const float* __restrict__ be2,
    const float* __restrict__ m2, const float* __restrict__ v2,
    float* __restrict__ beta1, float* __restrict__ beta2,
    unsigned short* __restrict__ w1b, unsigned short* __restrict__ w2f)
{
  int t = blockIdx.x * 256 + threadIdx.x;
  if (t < 139264) {   // w2 fragments: 17 ks * 16 ct * 64 lanes * 8
    int j = t & 7, l = (t >> 3) & 63, g = t >> 9;
    int ct = g & 15, ks = g >> 4;
    int k = ks * 32 + (l >> 4) * 8 + j;
    int ch = ct * 16 + (l & 15);
    float val = 0.f;
    if (k < 528) {
      float s2 = g2[ch] * rsqrtf(v2[ch] + EPS);
      val = w2[ch * 528 + k] * s2;
    }
    w2f[t] = f2bf(val);
  }
  if (t < 8192) {     // w1 fragments: 8 ks * 2 ct * 64 lanes * 8
    int j = t & 7, l = (t >> 3) & 63, g = t >> 9;
    int ct = g & 1, ks = g >> 1;
    int c = ks * 32 + (l >> 4) * 8 + j;
    int m = ct * 16 + (l & 15);
    float s1 = g1[m] * rsqrtf(v1[m] + EPS);
    w1b[t] = f2bf(w1[m * 256 + c] * s1);
  }
  if (t < 32) {
    float s1 = g1[t] * rsqrtf(v1[t] + EPS);
    beta1[t] = (b1[t] - m1[t]) * s1 + be1[t];
  }
  if (t < 256) {
    float s2 = g2[t] * rsqrtf(v2[t] + EPS);
    beta2[t] = (b2[t] - m2[t]) * s2 + be2[t];
  }
}

// Write diag I (reference order, len 32-I at base(I)) from register y-row.
template<int I>
__device__ __forceinline__ void do_diag(const float* __restrict__ y,
                                        unsigned short* __restrict__ pr)
{
  constexpr int L = 32 - I;
  constexpr int base = 32 * I - (I * (I - 1)) / 2;
  float p[L];
#pragma unroll
  for (int j = 0; j < L; ++j) p[j] = y[I + j] * y[j];
  constexpr int s = (base & 1) ? 1 : 0;
  if constexpr (s != 0) pr[base] = f2bf(p[0]);
#pragma unroll
  for (int j = s; j + 1 < L; j += 2)
    *(unsigned int*)&pr[base + j] =
        (unsigned int)f2bf(p[j]) | ((unsigned int)f2bf(p[j + 1]) << 16);
  if constexpr (((L - s) & 1) != 0) pr[base + L - 1] = f2bf(p[L - 1]);
}

// Diag pair {S, 31-S}: (32-S) + (S+1) = 33 products for every S.
template<int S>
__device__ __forceinline__ void do_pair(const float* __restrict__ y,
                                        unsigned short* __restrict__ pr)
{
  do_diag<S>(y, pr);
  do_diag<31 - S>(y, pr);
}

// ---------------------------------------------------------------------------
// Fused, 32-pixel tiles, 512 threads (8 waves), 2048 blocks, 4 blocks/CU
// = 32 waves/CU cap (TLP-doubling vs round 5's 4-wave blocks).
//  P0: x -> bf16 [px][276] tile, one pass (xt aliases pk)       (barrier)
//  P1: layer1 MFMA; wave pairs (w, w+4) redundantly compute the same
//      16x16 tile (identical bits -> benign same-value yf race)  (barrier)
//  P2: y-row -> regs; 16 diag-pair sets -> pk                    (barrier)
//  P3: layer2 MFMA, wave owns 2 ct x 2 pt, 17 ks + BN/relu + stores
// LDS: pk 35072B + yf 4352B = 39424B.
// ---------------------------------------------------------------------------
__global__ __launch_bounds__(512, 8) void k_fused(
    const float* __restrict__ x, const unsigned short* __restrict__ w1b,
    const float* __restrict__ beta1, const unsigned short* __restrict__ w2f,
    const float* __restrict__ beta2, float* __restrict__ out)
{
  __shared__ __align__(16) unsigned short pk[32 * 548];
  __shared__ __align__(8) float yf[32 * 34];
  int tid = threadIdx.x;
  int wv = tid >> 6, lane = tid & 63;
  int l15 = lane & 15, l4 = lane >> 4;
  int pb = blockIdx.x * 32;
  int b = pb >> 12, hw0 = pb & 4095;
  const float* xb = x + ((size_t)b << 20) + hw0;

  // ---- P0: stage x -> bf16 transposed tile (row = px, stride 276 u16)
  unsigned short* xt = pk;
  {
    int q = tid & 7;          // px quad (4*q .. 4*q+3)
    int c4 = tid >> 3;        // channel quad (0..63), single pass
    float4 v[4];
#pragma unroll
    for (int i = 0; i < 4; ++i)
      v[i] = *(const float4*)&xb[(size_t)(4 * c4 + i) * 4096 + 4 * q];
#pragma unroll
    for (int s = 0; s < 4; ++s) {
      float e0 = ((const float*)&v[0])[s];
      float e1 = ((const float*)&v[1])[s];
      float e2 = ((const float*)&v[2])[s];
      float e3 = ((const float*)&v[3])[s];
      unsigned int lo = (unsigned int)f2bf(e0) | ((unsigned int)f2bf(e1) << 16);
      unsigned int hi = (unsigned int)f2bf(e2) | ((unsigned int)f2bf(e3) << 16);
      *(uint2*)&xt[(4 * q + s) * 276 + 4 * c4] = make_uint2(lo, hi);
    }
  }
  __syncthreads();

  // ---- P1: layer1 MFMA; tile t = wv&3 (pxt = t&1, mt = t>>1).
  // Waves w and w+4 compute the same tile; identical-value yf writes.
  {
    int t = wv & 3;
    int pxt = t & 1, mt = t >> 1;
    int px = pxt * 16 + l15;
    f32x4 acc1 = (f32x4){0.f, 0.f, 0.f, 0.f};
    const uint4* w1b4 = (const uint4*)w1b;
#pragma unroll
    for (int ks = 0; ks < 8; ++ks) {
      union { uint4 q; bf16x8 v; } A, B;
      A.q = w1b4[(ks * 2 + mt) * 64 + lane];
      const unsigned short* s = &xt[px * 276 + ks * 32 + l4 * 8];
      uint2 lo = *(const uint2*)s;
      uint2 hi = *(const uint2*)(s + 4);
      B.q = make_uint4(lo.x, lo.y, hi.x, hi.y);
      acc1 = __builtin_amdgcn_mfma_f32_16x16x32_bf16(A.v, B.v, acc1, 0, 0, 0);
    }
    int m0 = mt * 16 + l4 * 4;
#pragma unroll
    for (int r = 0; r < 4; ++r)
      yf[px * 34 + m0 + r] = fmaxf(acc1[r] + beta1[m0 + r], 0.f);
  }
  __syncthreads();   // xt consumed AND yf ready; pk region free

  // ---- P2: register-sourced bilinear products, reference diag order.
  // 16 threads/px; set = diag pair {S, 31-S}, 33 products each.
  {
    int px2 = tid & 31, set = tid >> 5;
    const float* yr = &yf[px2 * 34];
    unsigned short* pr = &pk[px2 * 548];
    float y[32];
#pragma unroll
    for (int k = 0; k < 16; ++k) {
      float2 v = *(const float2*)&yr[2 * k];
      y[2 * k] = v.x; y[2 * k + 1] = v.y;
    }
    switch (set) {
      case 0:  do_pair<0>(y, pr);  break;
      case 1:  do_pair<1>(y, pr);  break;
      case 2:  do_pair<2>(y, pr);  break;
      case 3:  do_pair<3>(y, pr);  break;
      case 4:  do_pair<4>(y, pr);  break;
      case 5:  do_pair<5>(y, pr);  break;
      case 6:  do_pair<6>(y, pr);  break;
      case 7:  do_pair<7>(y, pr);  break;
      case 8:  do_pair<8>(y, pr);  break;
      case 9:  do_pair<9>(y, pr);  break;
      case 10: do_pair<10>(y, pr); break;
      case 11: do_pair<11>(y, pr); break;
      case 12: do_pair<12>(y, pr); break;
      case 13: do_pair<13>(y, pr); break;
      case 14: do_pair<14>(y, pr); break;
      default: do_pair<15>(y, pr); break;
    }
    // zero K-pad slots 528..543 (16 shorts per pixel): sets 0..3 only
    if (set < 4) {
      *(unsigned int*)&pr[528 + set * 4] = 0u;
      *(unsigned int*)&pr[530 + set * 4] = 0u;
    }
  }

  // beta2 loads issued before the barrier so their latency hides under P3
  float bet[2][4];
#pragma unroll
  for (int ci = 0; ci < 2; ++ci)
#pragma unroll
    for (int r = 0; r < 4; ++r)
      bet[ci][r] = beta2[(wv * 2 + ci) * 16 + l4 * 4 + r];

  __syncthreads();

  // ---- P3: layer2 MFMA.  Wave owns ct = 2wv..2wv+1, pt = 0..1.
  f32x4 acc[2][2];
#pragma unroll
  for (int a = 0; a < 2; ++a)
#pragma unroll
    for (int c = 0; c < 2; ++c)
      acc[a][c] = (f32x4){0.f, 0.f, 0.f, 0.f};

  const uint4* w2f4 = (const uint4*)w2f;
  int wbase = wv * 2;
#pragma unroll
  for (int ks = 0; ks < 17; ++ks) {
    union { uint4 q; bf16x8 v; } A[2], B[2];
#pragma unroll
    for (int ci = 0; ci < 2; ++ci)
      A[ci].q = w2f4[(ks * 16 + wbase + ci) * 64 + lane];
#pragma unroll
    for (int pt = 0; pt < 2; ++pt) {
      const unsigned short* src = &pk[(pt * 16 + l15) * 548 + ks * 32 + l4 * 8];
      uint2 lo = *(const uint2*)src;
      uint2 hi = *(const uint2*)(src + 4);
      B[pt].q = make_uint4(lo.x, lo.y, hi.x, hi.y);
    }
#pragma unroll
    for (int pt = 0; pt < 2; ++pt)
#pragma unroll
      for (int ci = 0; ci < 2; ++ci)
        acc[pt][ci] = __builtin_amdgcn_mfma_f32_16x16x32_bf16(
            A[ci].v, B[pt].v, acc[pt][ci], 0, 0, 0);
  }

  // ---- epilogue: BN fold + relu, coalesced stores
#pragma unroll
  for (int pt = 0; pt < 2; ++pt) {
    int hw = hw0 + pt * 16 + l15;
#pragma unroll
    for (int ci = 0; ci < 2; ++ci) {
      int ch = (wbase + ci) * 16 + l4 * 4;
#pragma unroll
      for (int r = 0; r < 4; ++r) {
        float v = fmaxf(acc[pt][ci][r] + bet[ci][r], 0.f);
        out[(((size_t)b * 256 + (ch + r)) << 12) + hw] = v;
      }
    }
  }
}

// ---------------------------------------------------------------------------
extern "C" void kernel_launch(void* const* d_in, const int* in_sizes, int n_in,
                              void* d_out, int out_size, void* d_ws, size_t ws_size,
                              hipStream_t stream)
{
  const float* x   = (const float*)d_in[0];
  const float* w1  = (const float*)d_in[1];
  const float* b1  = (const float*)d_in[2];
  const float* g1  = (const float*)d_in[3];
  const float* be1 = (const float*)d_in[4];
  const float* m1  = (const float*)d_in[5];
  const float* v1  = (const float*)d_in[6];
  const float* w2  = (const float*)d_in[7];
  const float* b2  = (const float*)d_in[8];
  const float* g2  = (const float*)d_in[9];
  const float* be2 = (const float*)d_in[10];
  const float* m2  = (const float*)d_in[11];
  const float* v2  = (const float*)d_in[12];

  char* ws = (char*)d_ws;
  float*          beta1 = (float*)(ws);                  // 128 B
  float*          beta2 = (float*)(ws + 128);            // 1024 B
  unsigned short* w1b   = (unsigned short*)(ws + 1152);  // 16384 B
  unsigned short* w2f   = (unsigned short*)(ws + 17536); // 278528 B
  float* out = (float*)d_out;

  k_prep<<<dim3(544), dim3(256), 0, stream>>>(
      w1, b1, g1, be1, m1, v1, w2, b2, g2, be2, m2, v2, beta1, beta2, w1b, w2f);
  k_fused<<<dim3(2048), dim3(512), 0, stream>>>(x, w1b, beta1, w2f, beta2, out);
}

// Round 7
// 48.600 us; speedup vs baseline: 1.0760x; 1.0760x over previous
//
#include <hip/hip_runtime.h>

#define EPS 1e-5f

typedef float f32x4 __attribute__((ext_vector_type(4)));
typedef short bf16x8 __attribute__((ext_vector_type(8)));

__device__ __forceinline__ unsigned short f2bf(float f) {
  unsigned int u = __builtin_bit_cast(unsigned int, f);
  u = (u + 0x7FFFu + ((u >> 16) & 1u)) >> 16;
  return (unsigned short)u;
}

// ---------------------------------------------------------------------------
// Prep (verified): fold BN into weights; emit both weight matrices in MFMA
// A-fragment layout (bf16), REFERENCE k-order.
// Frag element: idx = ((ks*CT + ct)*64 + lane)*8 + j
//   <-> A[ch = ct*16 + (lane&15)][k = ks*32 + (lane>>4)*8 + j]
// w2: K 528 -> 544 zero-padded (17 ks, CT=16).  w1: K=256 exact (8 ks, CT=2).
// ---------------------------------------------------------------------------
__global__ __launch_bounds__(256) void k_prep(
    const float* __restrict__ w1, const float* __restrict__ b1,
    const float* __restrict__ g1, const float* __restrict__ be1,
    const float* __restrict__ m1, const float* __restrict__ v1,
    const float* __restrict__ w2, const float* __restrict__ b2,
    const float* __restrict__ g2, const float* __restrict__ be2,
    const float* __restrict__ m2, const float* __restrict__ v2,
    float* __restrict__ beta1, float* __restrict__ beta2,
    unsigned short* __restrict__ w1b, unsigned short* __restrict__ w2f)
{
  int t = blockIdx.x * 256 + threadIdx.x;
  if (t < 139264) {   // w2 fragments: 17 ks * 16 ct * 64 lanes * 8
    int j = t & 7, l = (t >> 3) & 63, g = t >> 9;
    int ct = g & 15, ks = g >> 4;
    int k = ks * 32 + (l >> 4) * 8 + j;
    int ch = ct * 16 + (l & 15);
    float val = 0.f;
    if (k < 528) {
      float s2 = g2[ch] * rsqrtf(v2[ch] + EPS);
      val = w2[ch * 528 + k] * s2;
    }
    w2f[t] = f2bf(val);
  }
  if (t < 8192) {     // w1 fragments: 8 ks * 2 ct * 64 lanes * 8
    int j = t & 7, l = (t >> 3) & 63, g = t >> 9;
    int ct = g & 1, ks = g >> 1;
    int c = ks * 32 + (l >> 4) * 8 + j;
    int m = ct * 16 + (l & 15);
    float s1 = g1[m] * rsqrtf(v1[m] + EPS);
    w1b[t] = f2bf(w1[m * 256 + c] * s1);
  }
  if (t < 32) {
    float s1 = g1[t] * rsqrtf(v1[t] + EPS);
    beta1[t] = (b1[t] - m1[t]) * s1 + be1[t];
  }
  if (t < 256) {
    float s2 = g2[t] * rsqrtf(v2[t] + EPS);
    beta2[t] = (b2[t] - m2[t]) * s2 + be2[t];
  }
}

// Write diag I (reference order, len 32-I at base(I)) from register y-row.
template<int I>
__device__ __forceinline__ void do_diag(const float* __restrict__ y,
                                        unsigned short* __restrict__ pr)
{
  constexpr int L = 32 - I;
  constexpr int base = 32 * I - (I * (I - 1)) / 2;
  float p[L];
#pragma unroll
  for (int j = 0; j < L; ++j) p[j] = y[I + j] * y[j];
  constexpr int s = (base & 1) ? 1 : 0;
  if constexpr (s != 0) pr[base] = f2bf(p[0]);
#pragma unroll
  for (int j = s; j + 1 < L; j += 2)
    *(unsigned int*)&pr[base + j] =
        (unsigned int)f2bf(p[j]) | ((unsigned int)f2bf(p[j + 1]) << 16);
  if constexpr (((L - s) & 1) != 0) pr[base + L - 1] = f2bf(p[L - 1]);
}

// Balanced set: diags {S, 31-S, S+8, 23-S} = 66 products for every S.
template<int S>
__device__ __forceinline__ void do_set(const float* __restrict__ y,
                                       unsigned short* __restrict__ pr)
{
  do_diag<S>(y, pr);
  do_diag<31 - S>(y, pr);
  do_diag<S + 8>(y, pr);
  do_diag<23 - S>(y, pr);
}

// ---------------------------------------------------------------------------
// Fused, 32-pixel tiles (2048 blocks, 4 blocks/CU), XCD-aware swizzle:
// orig = (g&7)*256 + (g>>3), so XCD k (= g%8) owns orig [256k, 256k+256)
// = one contiguous 8.4MB slab of x/out -> dense HBM chunks per XCD.
//  P0: x -> bf16 [px][276] tile (xt aliases pk)              (barrier)
//  P1: layer1 MFMA -> yf f32 [px][34]                        (barrier)
//  P2: y-row -> regs; static diag products -> pk              (barrier)
//  P3: layer2 MFMA 17 ks x 4 ct x 2 pt per wave + BN/relu + stores
// LDS: pk 35072B + yf 4352B = 39424B.
// ---------------------------------------------------------------------------
__global__ __launch_bounds__(256, 4) void k_fused(
    const float* __restrict__ x, const unsigned short* __restrict__ w1b,
    const float* __restrict__ beta1, const unsigned short* __restrict__ w2f,
    const float* __restrict__ beta2, float* __restrict__ out)
{
  __shared__ __align__(16) unsigned short pk[32 * 548];
  __shared__ __align__(8) float yf[32 * 34];
  int tid = threadIdx.x;
  int wv = tid >> 6, lane = tid & 63;
  int l15 = lane & 15, l4 = lane >> 4;
  int g = blockIdx.x;
  int orig = ((g & 7) << 8) + (g >> 3);   // bijective XCD swizzle (2048 % 8 == 0)
  int pb = orig * 32;
  int b = pb >> 12, hw0 = pb & 4095;
  const float* xb = x + ((size_t)b << 20) + hw0;

  // ---- P0: stage x -> bf16 transposed tile (row = px, stride 276 u16)
  unsigned short* xt = pk;
  {
    int q = tid & 7;          // px quad (4*q .. 4*q+3)
    int cg = tid >> 3;        // channel-quad index within pass (0..31)
#pragma unroll
    for (int pass = 0; pass < 2; ++pass) {
      int c4 = cg + pass * 32;    // ch = 4*c4 + i
      float4 v[4];
#pragma unroll
      for (int i = 0; i < 4; ++i)
        v[i] = *(const float4*)&xb[(size_t)(4 * c4 + i) * 4096 + 4 * q];
#pragma unroll
      for (int s = 0; s < 4; ++s) {
        float e0 = ((const float*)&v[0])[s];
        float e1 = ((const float*)&v[1])[s];
        float e2 = ((const float*)&v[2])[s];
        float e3 = ((const float*)&v[3])[s];
        unsigned int lo = (unsigned int)f2bf(e0) | ((unsigned int)f2bf(e1) << 16);
        unsigned int hi = (unsigned int)f2bf(e2) | ((unsigned int)f2bf(e3) << 16);
        *(uint2*)&xt[(4 * q + s) * 276 + 4 * c4] = make_uint2(lo, hi);
      }
    }
  }
  __syncthreads();

  // ---- P1: layer1 MFMA; wave = (pxt = wv&1, mt = wv>>1) 16x16 tile
  {
    int pxt = wv & 1, mt = wv >> 1;
    int px = pxt * 16 + l15;
    f32x4 acc1 = (f32x4){0.f, 0.f, 0.f, 0.f};
    const uint4* w1b4 = (const uint4*)w1b;
#pragma unroll
    for (int ks = 0; ks < 8; ++ks) {
      union { uint4 q; bf16x8 v; } A, B;
      A.q = w1b4[(ks * 2 + mt) * 64 + lane];
      const unsigned short* s = &xt[px * 276 + ks * 32 + l4 * 8];
      uint2 lo = *(const uint2*)s;
      uint2 hi = *(const uint2*)(s + 4);
      B.q = make_uint4(lo.x, lo.y, hi.x, hi.y);
      acc1 = __builtin_amdgcn_mfma_f32_16x16x32_bf16(A.v, B.v, acc1, 0, 0, 0);
    }
    int m0 = mt * 16 + l4 * 4;
#pragma unroll
    for (int r = 0; r < 4; ++r)
      yf[px * 34 + m0 + r] = fmaxf(acc1[r] + beta1[m0 + r], 0.f);
  }
  __syncthreads();   // xt consumed AND yf ready; pk region free

  // ---- P2: register-sourced bilinear products, reference diag order
  {
    int px2 = tid & 31, set = tid >> 5;
    const float* yr = &yf[px2 * 34];
    unsigned short* pr = &pk[px2 * 548];
    float y[32];
#pragma unroll
    for (int k = 0; k < 16; ++k) {
      float2 v = *(const float2*)&yr[2 * k];
      y[2 * k] = v.x; y[2 * k + 1] = v.y;
    }
    switch (set) {
      case 0: do_set<0>(y, pr); break;
      case 1: do_set<1>(y, pr); break;
      case 2: do_set<2>(y, pr); break;
      case 3: do_set<3>(y, pr); break;
      case 4: do_set<4>(y, pr); break;
      case 5: do_set<5>(y, pr); break;
      case 6: do_set<6>(y, pr); break;
      default: do_set<7>(y, pr); break;
    }
    // zero K-pad slots 528..543 (16 shorts per pixel): sets 0..3 only
    if (set < 4) {
      *(unsigned int*)&pr[528 + set * 4] = 0u;
      *(unsigned int*)&pr[530 + set * 4] = 0u;
    }
  }

  // beta2 loads issued before the barrier so their latency hides under P3
  float bet[4][4];
#pragma unroll
  for (int ctl = 0; ctl < 4; ++ctl)
#pragma unroll
    for (int r = 0; r < 4; ++r)
      bet[ctl][r] = beta2[(wv * 4 + ctl) * 16 + l4 * 4 + r];

  __syncthreads();

  // ---- P3: layer2 MFMA.  Wave owns ct = wv*4..wv*4+3, pt = 0..1.
  f32x4 acc[2][4];
#pragma unroll
  for (int a = 0; a < 2; ++a)
#pragma unroll
    for (int c = 0; c < 4; ++c)
      acc[a][c] = (f32x4){0.f, 0.f, 0.f, 0.f};

  const uint4* w2f4 = (const uint4*)w2f;
#pragma unroll
  for (int ks = 0; ks < 17; ++ks) {
    union { uint4 q; bf16x8 v; } A[4], B[2];
#pragma unroll
    for (int ctl = 0; ctl < 4; ++ctl)
      A[ctl].q = w2f4[(ks * 16 + wv * 4 + ctl) * 64 + lane];
#pragma unroll
    for (int pt = 0; pt < 2; ++pt) {
      const unsigned short* src = &pk[(pt * 16 + l15) * 548 + ks * 32 + l4 * 8];
      uint2 lo = *(const uint2*)src;
      uint2 hi = *(const uint2*)(src + 4);
      B[pt].q = make_uint4(lo.x, lo.y, hi.x, hi.y);
    }
#pragma unroll
    for (int pt = 0; pt < 2; ++pt)
#pragma unroll
      for (int ctl = 0; ctl < 4; ++ctl)
        acc[pt][ctl] = __builtin_amdgcn_mfma_f32_16x16x32_bf16(
            A[ctl].v, B[pt].v, acc[pt][ctl], 0, 0, 0);
  }

  // ---- epilogue: BN fold + relu, coalesced stores
#pragma unroll
  for (int pt = 0; pt < 2; ++pt) {
    int hw = hw0 + pt * 16 + l15;
#pragma unroll
    for (int ctl = 0; ctl < 4; ++ctl) {
      int ch = (wv * 4 + ctl) * 16 + l4 * 4;
#pragma unroll
      for (int r = 0; r < 4; ++r) {
        float v = fmaxf(acc[pt][ctl][r] + bet[ctl][r], 0.f);
        out[(((size_t)b * 256 + (ch + r)) << 12) + hw] = v;
      }
    }
  }
}

// ---------------------------------------------------------------------------
extern "C" void kernel_launch(void* const* d_in, const int* in_sizes, int n_in,
                              void* d_out, int out_size, void* d_ws, size_t ws_size,
                              hipStream_t stream)
{
  const float* x   = (const float*)d_in[0];
  const float* w1  = (const float*)d_in[1];
  const float* b1  = (const float*)d_in[2];
  const float* g1  = (const float*)d_in[3];
  const float* be1 = (const float*)d_in[4];
  const float* m1  = (const float*)d_in[5];
  const float* v1  = (const float*)d_in[6];
  const float* w2  = (const float*)d_in[7];
  const float* b2  = (const float*)d_in[8];
  const float* g2  = (const float*)d_in[9];
  const float* be2 = (const float*)d_in[10];
  const float* m2  = (const float*)d_in[11];
  const float* v2  = (const float*)d_in[12];

  char* ws = (char*)d_ws;
  float*          beta1 = (float*)(ws);                  // 128 B
  float*          beta2 = (float*)(ws + 128);            // 1024 B
  unsigned short* w1b   = (unsigned short*)(ws + 1152);  // 16384 B
  unsigned short* w2f   = (unsigned short*)(ws + 17536); // 278528 B
  float* out = (float*)d_out;

  k_prep<<<dim3(544), dim3(256), 0, stream>>>(
      w1, b1, g1, be1, m1, v1, w2, b2, g2, be2, m2, v2, beta1, beta2, w1b, w2f);
  k_fused<<<dim3(2048), dim3(256), 0, stream>>>(x, w1b, beta1, w2f, beta2, out);
}